// Round 3
// baseline (1287.811 us; speedup 1.0000x reference)
//
#include <hip/hip_runtime.h>
#include <stdint.h>

// PyramidAttention gfx950 — round 3: barrier-free flash attention.
// Each wave owns (16 rows) x (private l-stream of 3392): softmax stats are
// wave-local, K-loop has no __syncthreads. 4 virtual l-splits merged at end.

typedef __attribute__((ext_vector_type(8))) short bf16x8;
typedef __attribute__((ext_vector_type(4))) float f32x4;
typedef unsigned short ushort_t;

#define L_TOT 13326
#define L_PAD3 13568   // 4 streams * 3392
#define LS_LEN 3392    // l per stream (106 iters of 32)
#define NITER 106
#define NPIX  4096
#define NVS   4        // virtual splits (2 block-splits x 2 wave-streams)

__device__ __forceinline__ float cubw(float d) {
  d = fabsf(d);
  if (d <= 1.f) return (1.25f * d - 2.25f) * d * d + 1.f;          // A=-0.75
  if (d < 2.f)  return ((-0.75f * d + 3.75f) * d - 6.f) * d + 3.f;
  return 0.f;
}

__device__ __forceinline__ void decode_l(int l, int& S, int& off) {
  if (l < 4096)       { S = 64; off = 0; }
  else if (l < 7345)  { S = 57; off = 4096; }
  else if (l < 9946)  { S = 51; off = 7345; }
  else if (l < 11882) { S = 44; off = 9946; }
  else                { S = 38; off = 11882; }
}

__device__ __forceinline__ ushort_t f2bf(float f) {
  union { float f; uint32_t u; } v; v.f = f;
  uint32_t r = (v.u + 0x7fffu + ((v.u >> 16) & 1u)) >> 16;  // RNE
  return (ushort_t)r;
}

__device__ __forceinline__ float preluf(float x, float a) { return x >= 0.f ? x : a * x; }

// ---------------- K1: bicubic resize (align_corners=True, border clamp) ----------------
__global__ void k_resize(const float* __restrict__ inref, float* __restrict__ refbuf, int n) {
  int idx = blockIdx.x * 256 + threadIdx.x;
  if (idx >= n) return;                      // n = 2*64*L_TOT, idx -> (b*64+c, l)
  int l = idx % L_TOT; int bc = idx / L_TOT;
  int S, off; decode_l(l, S, off);
  int li = l - off; int ly = li / S, lx = li % S;
  float val;
  if (S == 64) {
    val = inref[(size_t)bc * 4096 + ly * 64 + lx];
  } else {
    float sc = (float)(63.0 / (double)(S - 1));
    float sy = (float)ly * sc, sx = (float)lx * sc;
    int iy = (int)floorf(sy), ix = (int)floorf(sx);
    float fy = sy - (float)iy, fx = sx - (float)ix;
    float wy[4] = { cubw(fy + 1.f), cubw(fy), cubw(1.f - fy), cubw(2.f - fy) };
    float wx[4] = { cubw(fx + 1.f), cubw(fx), cubw(1.f - fx), cubw(2.f - fx) };
    val = 0.f;
    for (int t = 0; t < 4; ++t) {
      int ty = iy - 1 + t; ty = ty < 0 ? 0 : (ty > 63 ? 63 : ty);
      float rv = 0.f;
      for (int u = 0; u < 4; ++u) {
        int tx = ix - 1 + u; tx = tx < 0 ? 0 : (tx > 63 ? 63 : tx);
        rv += wx[u] * inref[(size_t)bc * 4096 + ty * 64 + tx];
      }
      val += wy[t] * rv;
    }
  }
  refbuf[(size_t)bc * L_TOT + l] = val;
}

// ---------------- K2: conv1x1 (Wm->mref 32ch, Wa->aref 64ch) + prelu ----------------
__global__ void k_convref(const float* __restrict__ refbuf,
                          const float* __restrict__ Wm, const float* __restrict__ bm,
                          const float* __restrict__ Wa, const float* __restrict__ ba,
                          const float* __restrict__ ap,
                          float* __restrict__ mref, float* __restrict__ aref, int n) {
  int idx = blockIdx.x * 256 + threadIdx.x;
  if (idx >= n) return;                      // n = 2*96*L_TOT
  int l = idx % L_TOT; int ch = (idx / L_TOT) % 96; int b = idx / (96 * L_TOT);
  float a = ap[0];
  const float* base = refbuf + (size_t)b * 64 * L_TOT + l;
  const float* Wrow; float acc;
  if (ch < 32) { Wrow = Wm + ch * 64; acc = bm[ch]; }
  else         { Wrow = Wa + (ch - 32) * 64; acc = ba[ch - 32]; }
  for (int c = 0; c < 64; ++c) acc += Wrow[c] * base[(size_t)c * L_TOT];
  acc = preluf(acc, a);
  if (ch < 32) mref[(size_t)(b * 32 + ch) * L_TOT + l] = acc;
  else         aref[(size_t)(b * 64 + ch - 32) * L_TOT + l] = acc;
}

// ---------------- K3: match_base = prelu(Wb@input+bb) ----------------
__global__ void k_mb(const float* __restrict__ input, const float* __restrict__ Wb,
                     const float* __restrict__ bb, const float* __restrict__ ap,
                     float* __restrict__ mbb, int n) {
  int idx = blockIdx.x * 256 + threadIdx.x;
  if (idx >= n) return;                      // n = 2*32*NPIX
  int p = idx % NPIX; int cm = (idx / NPIX) % 32; int b = idx / (32 * NPIX);
  float a = ap[0];
  float acc = bb[cm];
  for (int c = 0; c < 64; ++c) acc += Wb[cm * 64 + c] * input[(size_t)(b * 64 + c) * NPIX + p];
  mbb[(size_t)(b * 32 + cm) * NPIX + p] = preluf(acc, a);
}

// ---------------- K4a: per-position sum of squares of mref ----------------
__global__ void k_ssq(const float* __restrict__ mref, float* __restrict__ ssq, int n) {
  int idx = blockIdx.x * 256 + threadIdx.x;
  if (idx >= n) return;                      // n = 2*L_TOT
  int l = idx % L_TOT; int b = idx / L_TOT;
  float s = 0.f;
  for (int c = 0; c < 32; ++c) { float v = mref[(size_t)(b * 32 + c) * L_TOT + l]; s += v * v; }
  ssq[idx] = s;
}

// ---------------- K4b: 3x3 window sum -> 1/max(sqrt, 1e-4) ----------------
__global__ void k_invn(const float* __restrict__ ssq, float* __restrict__ invn, int n) {
  int idx = blockIdx.x * 256 + threadIdx.x;
  if (idx >= n) return;
  int l = idx % L_TOT; int b = idx / L_TOT;
  int S, off; decode_l(l, S, off);
  int li = l - off; int ly = li / S, lx = li % S;
  float acc = 0.f;
  for (int dy = -1; dy <= 1; ++dy) {
    int ny = ly + dy; if (ny < 0 || ny >= S) continue;
    for (int dx = -1; dx <= 1; ++dx) {
      int nx = lx + dx; if (nx < 0 || nx >= S) continue;
      acc += ssq[(size_t)b * L_TOT + off + ny * S + nx];
    }
  }
  float nrm = sqrtf(acc); nrm = fmaxf(nrm, 1e-4f);
  invn[idx] = 1.f / nrm;
}

// ---------------- K5: B im2col (normalized key patches) bf16 [b][l][288] ----------------
__global__ void k_bim(const float* __restrict__ mref, const float* __restrict__ invn,
                      ushort_t* __restrict__ Bm, int n) {
  int idx = blockIdx.x * 256 + threadIdx.x;
  if (idx >= n) return;                      // n = 2*L_TOT*288
  int k = idx % 288; int l = (idx / 288) % L_TOT; int b = idx / (288 * L_TOT);
  int c = k / 9; int r = k % 9; int dy = r / 3 - 1, dx = r % 3 - 1;
  int S, off; decode_l(l, S, off);
  int li = l - off; int ly = li / S, lx = li % S;
  int ny = ly + dy, nx = lx + dx;
  float v = 0.f;
  if (ny >= 0 && ny < S && nx >= 0 && nx < S)
    v = mref[(size_t)(b * 32 + c) * L_TOT + off + ny * S + nx] * invn[(size_t)b * L_TOT + l];
  Bm[(size_t)(b * L_TOT + l) * 288 + k] = f2bf(v);
}

// ---------------- K6: A im2col (query patches) bf16 [b][p][288] ----------------
__global__ void k_aim(const float* __restrict__ mbb, ushort_t* __restrict__ Am, int n) {
  int idx = blockIdx.x * 256 + threadIdx.x;
  if (idx >= n) return;                      // n = 2*NPIX*288
  int k = idx % 288; int p = (idx / 288) % NPIX; int b = idx / (288 * NPIX);
  int c = k / 9; int r = k % 9; int dy = r / 3 - 1, dx = r % 3 - 1;
  int y = p / 64, x = p % 64;
  int ny = y + dy, nx = x + dx;
  float v = 0.f;
  if (ny >= 0 && ny < 64 && nx >= 0 && nx < 64)
    v = mbb[(size_t)(b * 32 + c) * NPIX + ny * 64 + nx];
  Am[(size_t)(b * NPIX + p) * 288 + k] = f2bf(v);
}

// ---------------- K7: R im2col (value patches), col-major over l, zero-padded ----------------
__global__ void k_rim(const float* __restrict__ aref, ushort_t* __restrict__ Rm, int n) {
  int idx = blockIdx.x * 256 + threadIdx.x;
  if (idx >= n) return;                      // n = 2*576*L_PAD3
  int l = idx % L_PAD3; int col = (idx / L_PAD3) % 576; int b = idx / (576 * L_PAD3);
  float v = 0.f;
  if (l < L_TOT) {
    int c = col / 9; int r = col % 9; int dy = r / 3 - 1, dx = r % 3 - 1;
    int S, off; decode_l(l, S, off);
    int li = l - off; int ly = li / S, lx = li % S;
    int ny = ly + dy, nx = lx + dx;
    if (ny >= 0 && ny < S && nx >= 0 && nx < S)
      v = aref[(size_t)(b * 64 + c) * L_TOT + off + ny * S + nx];
  }
  Rm[(size_t)(b * 576 + col) * L_PAD3 + l] = f2bf(v);
}

// ---------------- K8: barrier-free flash attention ----------------
// grid 512: blockIdx -> tile(7b) | s(1b) | b(1b). 256 thr = 4 waves.
// wave w: rb=w&1 (row-block of 16), ls=w>>1 (l-stream). vsplit = s*2+ls.
// Wave-private (m,l,acc) over its 3392-l stream; no __syncthreads in K-loop.
__global__ __launch_bounds__(256, 2) void k_attn(const ushort_t* __restrict__ Am,
                                                 const ushort_t* __restrict__ Bm,
                                                 const ushort_t* __restrict__ Rm,
                                                 float* __restrict__ Og,
                                                 float* __restrict__ Om,
                                                 float* __restrict__ Ol) {
  __shared__ ushort_t Pw[4][16][40];   // wave-private P tile [row][l] (+8 pad)
  int tid = threadIdx.x;
  int tile = blockIdx.x & 127; int s = (blockIdx.x >> 7) & 1; int b = blockIdx.x >> 8;
  int p0 = tile * 32;
  int wave = tid >> 6, lane = tid & 63, quad = lane >> 4, ln = lane & 15;
  int rb = wave & 1, ls = wave >> 1;
  int lsbase = (s * 2 + ls) * LS_LEN;

  // A fragments resident (9 k-steps over K=288), rows p0 + rb*16 + ln
  bf16x8 af[9];
  {
    const ushort_t* arow = Am + (size_t)(b * NPIX + p0 + rb * 16 + ln) * 288;
    #pragma unroll
    for (int kk = 0; kk < 9; ++kk) af[kk] = *(const bf16x8*)(arow + kk * 32 + quad * 8);
  }

  f32x4 acc[36];
  #pragma unroll
  for (int t = 0; t < 36; ++t) { acc[t][0] = acc[t][1] = acc[t][2] = acc[t][3] = 0.f; }
  float mrun[4], lrun[4];
  #pragma unroll
  for (int r = 0; r < 4; ++r) { mrun[r] = -1e30f; lrun[r] = 0.f; }

  const size_t rcolstride = (size_t)16 * L_PAD3;
  const ushort_t* rbase = Rm + ((size_t)(b * 576 + ln) * L_PAD3 + lsbase + quad * 8);

  for (int c = 0; c < NITER; ++c) {
    int lb = lsbase + c * 32;
    // ---- S tile: 16 rows x 32 l (2 col-blocks) ----
    int col0 = lb + ln, col1 = col0 + 16;
    bool v0 = col0 < L_TOT, v1 = col1 < L_TOT;
    const ushort_t* b0 = Bm + (size_t)(b * L_TOT + (v0 ? col0 : 0)) * 288 + quad * 8;
    const ushort_t* b1 = Bm + (size_t)(b * L_TOT + (v1 ? col1 : 0)) * 288 + quad * 8;
    f32x4 s0, s1;
    s0[0] = s0[1] = s0[2] = s0[3] = 0.f;
    s1[0] = s1[1] = s1[2] = s1[3] = 0.f;
    #pragma unroll
    for (int kk = 0; kk < 9; ++kk) {
      bf16x8 f0 = *(const bf16x8*)(b0 + kk * 32);
      bf16x8 f1 = *(const bf16x8*)(b1 + kk * 32);
      s0 = __builtin_amdgcn_mfma_f32_16x16x32_bf16(af[kk], f0, s0, 0, 0, 0);
      s1 = __builtin_amdgcn_mfma_f32_16x16x32_bf16(af[kk], f1, s1, 0, 0, 0);
    }
    // ---- wave-local chunk max (in-lane over 2 cols, shfl over 16 lanes) ----
    float cm[4];
    #pragma unroll
    for (int r = 0; r < 4; ++r)
      cm[r] = fmaxf(v0 ? s0[r] : -1e30f, v1 ? s1[r] : -1e30f);
    #pragma unroll
    for (int m = 1; m <= 8; m <<= 1)
      #pragma unroll
      for (int r = 0; r < 4; ++r) cm[r] = fmaxf(cm[r], __shfl_xor(cm[r], m));
    float al[4]; bool chg = false;
    #pragma unroll
    for (int r = 0; r < 4; ++r) {
      if (cm[r] > mrun[r]) {
        al[r] = __expf(10.f * (mrun[r] - cm[r]));
        mrun[r] = cm[r];
        chg = true;
      } else al[r] = 1.f;
    }
    // ---- P = exp(10(s-m)), row sums, write wave-private LDS ----
    float ps[4];
    #pragma unroll
    for (int r = 0; r < 4; ++r) {
      float p0v = v0 ? __expf(10.f * (s0[r] - mrun[r])) : 0.f;
      float p1v = v1 ? __expf(10.f * (s1[r] - mrun[r])) : 0.f;
      Pw[wave][quad * 4 + r][ln] = f2bf(p0v);
      Pw[wave][quad * 4 + r][16 + ln] = f2bf(p1v);
      ps[r] = p0v + p1v;
    }
    #pragma unroll
    for (int m = 1; m <= 8; m <<= 1)
      #pragma unroll
      for (int r = 0; r < 4; ++r) ps[r] += __shfl_xor(ps[r], m);
    #pragma unroll
    for (int r = 0; r < 4; ++r) lrun[r] = lrun[r] * al[r] + ps[r];
    // ---- rescale acc only when max moved anywhere in the wave ----
    if (__any(chg)) {
      #pragma unroll
      for (int t = 0; t < 36; ++t)
        #pragma unroll
        for (int r = 0; r < 4; ++r) acc[t][r] *= al[r];
    }
    // ---- Z-GEMM: P(16x32) @ R(32x576) ----
    bf16x8 pf = *(const bf16x8*)&Pw[wave][ln][quad * 8];
    const ushort_t* rp = rbase + c * 32;
    #pragma unroll
    for (int t = 0; t < 36; ++t) {
      bf16x8 rf = *(const bf16x8*)(rp + (size_t)t * rcolstride);
      acc[t] = __builtin_amdgcn_mfma_f32_16x16x32_bf16(pf, rf, acc[t], 0, 0, 0);
    }
  }

  // ---- epilogue: unnormalized O + per-row stats for this vsplit ----
  int v = s * 2 + ls;
  #pragma unroll
  for (int t = 0; t < 36; ++t) {
    int colg = t * 16 + ln;
    #pragma unroll
    for (int r = 0; r < 4; ++r) {
      int row = p0 + rb * 16 + quad * 4 + r;
      Og[((size_t)(v * 2 + b) * NPIX + row) * 576 + colg] = acc[t][r];
    }
  }
  if (ln == 0) {
    #pragma unroll
    for (int r = 0; r < 4; ++r) {
      int row = p0 + rb * 16 + quad * 4 + r;
      Om[(size_t)(v * 2 + b) * NPIX + row] = mrun[r];
      Ol[(size_t)(v * 2 + b) * NPIX + row] = lrun[r];
    }
  }
}

// ---------------- K9: per-pixel merge scales across the 4 vsplits ----------------
__global__ void k_scales(const float* __restrict__ Om, const float* __restrict__ Ol,
                         float* __restrict__ sc, int n) {
  int idx = blockIdx.x * 256 + threadIdx.x;
  if (idx >= n) return;                      // n = 2*NPIX; idx = b*NPIX+p
  int b = idx / NPIX; int p = idx % NPIX;
  float m[NVS], l[NVS];
  float M = -1e30f;
  for (int v = 0; v < NVS; ++v) {
    m[v] = Om[(size_t)(v * 2 + b) * NPIX + p];
    l[v] = Ol[(size_t)(v * 2 + b) * NPIX + p];
    M = fmaxf(M, m[v]);
  }
  float den = 0.f, e[NVS];
  for (int v = 0; v < NVS; ++v) { e[v] = expf(10.f * (m[v] - M)); den += l[v] * e[v]; }
  float inv = 1.f / den;
  for (int v = 0; v < NVS; ++v) sc[(size_t)(v * 2 + b) * NPIX + p] = e[v] * inv;
}

// ---------------- K9b: reduce the 4 vsplit partials into normalized Z ----------------
__global__ void k_reduce(const float* __restrict__ Og, const float* __restrict__ sc,
                         float* __restrict__ Zn, int n) {
  int idx = blockIdx.x * 256 + threadIdx.x;
  if (idx >= n) return;                      // n = 2*NPIX*576; idx = (b*NPIX+p)*576+col
  int bp = idx / 576;
  float acc = 0.f;
  for (int v = 0; v < NVS; ++v) {
    size_t o = (size_t)v * 2 * NPIX * 576;
    acc += Og[o + idx] * sc[(size_t)v * 2 * NPIX + bp];
  }
  Zn[idx] = acc;
}

// ---------------- K10: 9-tap gather (conv-transpose), /4, + residual ----------------
__global__ void k_final(const float* __restrict__ Zn, const float* __restrict__ input,
                        float* __restrict__ out, int n) {
  int idx = blockIdx.x * 256 + threadIdx.x;
  if (idx >= n) return;                      // n = 2*64*NPIX, idx = ((b*64+c)*64+y)*64+x
  int x = idx & 63; int y = (idx >> 6) & 63; int c = (idx >> 12) & 63; int b = idx >> 18;
  float acc = 0.f;
  for (int j = 0; j < 3; ++j) {
    int qy = y + 1 - j; if (qy < 0 || qy >= 64) continue;
    for (int i = 0; i < 3; ++i) {
      int qx = x + 1 - i; if (qx < 0 || qx >= 64) continue;
      acc += Zn[((size_t)b * NPIX + qy * 64 + qx) * 576 + c * 9 + j * 3 + i];
    }
  }
  out[idx] = 0.25f * acc + input[idx];
}

extern "C" void kernel_launch(void* const* d_in, const int* in_sizes, int n_in,
                              void* d_out, int out_size, void* d_ws, size_t ws_size,
                              hipStream_t stream) {
  (void)in_sizes; (void)n_in; (void)out_size; (void)ws_size;
  const float* input = (const float*)d_in[0];
  const float* inref = (const float*)d_in[1];
  const float* Wb = (const float*)d_in[2];
  const float* bb = (const float*)d_in[3];
  const float* Wm = (const float*)d_in[4];
  const float* bm = (const float*)d_in[5];
  const float* Wa = (const float*)d_in[6];
  const float* ba = (const float*)d_in[7];
  const float* ap = (const float*)d_in[8];
  float* out = (float*)d_out;

  char* ws = (char*)d_ws;
  size_t off = 0;
  auto alloc = [&](size_t bytes) -> char* {
    char* p = ws + off; off = (off + bytes + 255) & ~(size_t)255; return p;
  };
  // persistent region
  ushort_t* Am = (ushort_t*)alloc((size_t)2 * NPIX * 288 * 2);        // 4.7 MB
  ushort_t* Bm = (ushort_t*)alloc((size_t)2 * L_TOT * 288 * 2);       // 15.3 MB
  ushort_t* Rm = (ushort_t*)alloc((size_t)2 * 576 * L_PAD3 * 2);      // 31.3 MB
  float*    Zn = (float*)alloc((size_t)2 * NPIX * 576 * 4);           // 18.9 MB
  float*    Om = (float*)alloc((size_t)NVS * 2 * NPIX * 4);
  float*    Ol = (float*)alloc((size_t)NVS * 2 * NPIX * 4);
  float*    sc = (float*)alloc((size_t)NVS * 2 * NPIX * 4);
  // big region: early prep buffers alias Og (early buffers dead before k_attn)
  size_t og_bytes = (size_t)NVS * 2 * NPIX * 576 * 4;                 // 75.5 MB
  char* big = alloc(og_bytes);
  float* Og = (float*)big;
  size_t eoff = 0;
  auto ealloc = [&](size_t bytes) -> char* {
    char* p = big + eoff; eoff = (eoff + bytes + 255) & ~(size_t)255; return p;
  };
  float* refbuf = (float*)ealloc((size_t)2 * 64 * L_TOT * 4);
  float* mref   = (float*)ealloc((size_t)2 * 32 * L_TOT * 4);
  float* aref   = (float*)ealloc((size_t)2 * 64 * L_TOT * 4);
  float* mbb    = (float*)ealloc((size_t)2 * 32 * NPIX * 4);
  float* ssq    = (float*)ealloc((size_t)2 * L_TOT * 4);
  float* invn   = (float*)ealloc((size_t)2 * L_TOT * 4);
  // total ws ~ 146 MB

  int n1 = 2 * 64 * L_TOT;
  k_resize<<<(n1 + 255) / 256, 256, 0, stream>>>(inref, refbuf, n1);
  int n2 = 2 * 96 * L_TOT;
  k_convref<<<(n2 + 255) / 256, 256, 0, stream>>>(refbuf, Wm, bm, Wa, ba, ap, mref, aref, n2);
  int n3 = 2 * 32 * NPIX;
  k_mb<<<(n3 + 255) / 256, 256, 0, stream>>>(input, Wb, bb, ap, mbb, n3);
  int n4 = 2 * L_TOT;
  k_ssq<<<(n4 + 255) / 256, 256, 0, stream>>>(mref, ssq, n4);
  k_invn<<<(n4 + 255) / 256, 256, 0, stream>>>(ssq, invn, n4);
  int n5 = 2 * L_TOT * 288;
  k_bim<<<(n5 + 255) / 256, 256, 0, stream>>>(mref, invn, Bm, n5);
  int n6 = 2 * NPIX * 288;
  k_aim<<<(n6 + 255) / 256, 256, 0, stream>>>(mbb, Am, n6);
  int n7 = 2 * 576 * L_PAD3;
  k_rim<<<(n7 + 255) / 256, 256, 0, stream>>>(aref, Rm, n7);

  k_attn<<<512, 256, 0, stream>>>(Am, Bm, Rm, Og, Om, Ol);
  k_scales<<<(2 * NPIX + 255) / 256, 256, 0, stream>>>(Om, Ol, sc, 2 * NPIX);
  int nr = 2 * NPIX * 576;
  k_reduce<<<(nr + 255) / 256, 256, 0, stream>>>(Og, sc, Zn, nr);
  int no = 2 * 64 * NPIX;
  k_final<<<(no + 255) / 256, 256, 0, stream>>>(Zn, input, out, no);
}

// Round 4
// 830.247 us; speedup vs baseline: 1.5511x; 1.5511x over previous
//
#include <hip/hip_runtime.h>
#include <stdint.h>

// PyramidAttention gfx950 — round 4: m97-style LDS-staged fused attention.
// R staged via global_load_lds (async, no VGPRs) into double-buffered LDS with
// pre-swizzled global layout; B register-prefetched one chunk ahead; Kc=32;
// 2 barriers/chunk pace the pipeline (m97 structure). 2 l-splits, merge in final.

typedef __attribute__((ext_vector_type(8))) short bf16x8;
typedef __attribute__((ext_vector_type(4))) float f32x4;
typedef unsigned short ushort_t;

#define L_TOT  13326
#define L_PADB 13344   // 417 chunks * 32 (B matrix row pad)
#define NCHT   417     // total 32-l chunks
#define NPIX   4096
#define RCHUNK_E 18432 // R chunk elems (576 cols * 32 l)

__device__ __forceinline__ float cubw(float d) {
  d = fabsf(d);
  if (d <= 1.f) return (1.25f * d - 2.25f) * d * d + 1.f;          // A=-0.75
  if (d < 2.f)  return ((-0.75f * d + 3.75f) * d - 6.f) * d + 3.f;
  return 0.f;
}

__device__ __forceinline__ void decode_l(int l, int& S, int& off) {
  if (l < 4096)       { S = 64; off = 0; }
  else if (l < 7345)  { S = 57; off = 4096; }
  else if (l < 9946)  { S = 51; off = 7345; }
  else if (l < 11882) { S = 44; off = 9946; }
  else                { S = 38; off = 11882; }
}

__device__ __forceinline__ ushort_t f2bf(float f) {
  union { float f; uint32_t u; } v; v.f = f;
  uint32_t r = (v.u + 0x7fffu + ((v.u >> 16) & 1u)) >> 16;  // RNE
  return (ushort_t)r;
}

__device__ __forceinline__ float preluf(float x, float a) { return x >= 0.f ? x : a * x; }

__device__ __forceinline__ void gll16(const ushort_t* g, ushort_t* l) {
  __builtin_amdgcn_global_load_lds(
      (const __attribute__((address_space(1))) unsigned int*)g,
      (__attribute__((address_space(3))) unsigned int*)l, 16, 0, 0);
}

// ---------------- K1: bicubic resize (align_corners=True, border clamp) ----------------
__global__ void k_resize(const float* __restrict__ inref, float* __restrict__ refbuf, int n) {
  int idx = blockIdx.x * 256 + threadIdx.x;
  if (idx >= n) return;                      // n = 2*64*L_TOT, idx -> (b*64+c, l)
  int l = idx % L_TOT; int bc = idx / L_TOT;
  int S, off; decode_l(l, S, off);
  int li = l - off; int ly = li / S, lx = li % S;
  float val;
  if (S == 64) {
    val = inref[(size_t)bc * 4096 + ly * 64 + lx];
  } else {
    float sc = (float)(63.0 / (double)(S - 1));
    float sy = (float)ly * sc, sx = (float)lx * sc;
    int iy = (int)floorf(sy), ix = (int)floorf(sx);
    float fy = sy - (float)iy, fx = sx - (float)ix;
    float wy[4] = { cubw(fy + 1.f), cubw(fy), cubw(1.f - fy), cubw(2.f - fy) };
    float wx[4] = { cubw(fx + 1.f), cubw(fx), cubw(1.f - fx), cubw(2.f - fx) };
    val = 0.f;
    for (int t = 0; t < 4; ++t) {
      int ty = iy - 1 + t; ty = ty < 0 ? 0 : (ty > 63 ? 63 : ty);
      float rv = 0.f;
      for (int u = 0; u < 4; ++u) {
        int tx = ix - 1 + u; tx = tx < 0 ? 0 : (tx > 63 ? 63 : tx);
        rv += wx[u] * inref[(size_t)bc * 4096 + ty * 64 + tx];
      }
      val += wy[t] * rv;
    }
  }
  refbuf[(size_t)bc * L_TOT + l] = val;
}

// ---------------- K2: conv1x1 (Wm->mref 32ch, Wa->aref 64ch) + prelu ----------------
__global__ void k_convref(const float* __restrict__ refbuf,
                          const float* __restrict__ Wm, const float* __restrict__ bm,
                          const float* __restrict__ Wa, const float* __restrict__ ba,
                          const float* __restrict__ ap,
                          float* __restrict__ mref, float* __restrict__ aref, int n) {
  int idx = blockIdx.x * 256 + threadIdx.x;
  if (idx >= n) return;                      // n = 2*96*L_TOT
  int l = idx % L_TOT; int ch = (idx / L_TOT) % 96; int b = idx / (96 * L_TOT);
  float a = ap[0];
  const float* base = refbuf + (size_t)b * 64 * L_TOT + l;
  const float* Wrow; float acc;
  if (ch < 32) { Wrow = Wm + ch * 64; acc = bm[ch]; }
  else         { Wrow = Wa + (ch - 32) * 64; acc = ba[ch - 32]; }
  for (int c = 0; c < 64; ++c) acc += Wrow[c] * base[(size_t)c * L_TOT];
  acc = preluf(acc, a);
  if (ch < 32) mref[(size_t)(b * 32 + ch) * L_TOT + l] = acc;
  else         aref[(size_t)(b * 64 + ch - 32) * L_TOT + l] = acc;
}

// ---------------- K3: match_base = prelu(Wb@input+bb) ----------------
__global__ void k_mb(const float* __restrict__ input, const float* __restrict__ Wb,
                     const float* __restrict__ bb, const float* __restrict__ ap,
                     float* __restrict__ mbb, int n) {
  int idx = blockIdx.x * 256 + threadIdx.x;
  if (idx >= n) return;                      // n = 2*32*NPIX
  int p = idx % NPIX; int cm = (idx / NPIX) % 32; int b = idx / (32 * NPIX);
  float a = ap[0];
  float acc = bb[cm];
  for (int c = 0; c < 64; ++c) acc += Wb[cm * 64 + c] * input[(size_t)(b * 64 + c) * NPIX + p];
  mbb[(size_t)(b * 32 + cm) * NPIX + p] = preluf(acc, a);
}

// ---------------- K4a: per-position sum of squares of mref ----------------
__global__ void k_ssq(const float* __restrict__ mref, float* __restrict__ ssq, int n) {
  int idx = blockIdx.x * 256 + threadIdx.x;
  if (idx >= n) return;                      // n = 2*L_TOT
  int l = idx % L_TOT; int b = idx / L_TOT;
  float s = 0.f;
  for (int c = 0; c < 32; ++c) { float v = mref[(size_t)(b * 32 + c) * L_TOT + l]; s += v * v; }
  ssq[idx] = s;
}

// ---------------- K4b: 3x3 window sum -> 1/max(sqrt, 1e-4) ----------------
__global__ void k_invn(const float* __restrict__ ssq, float* __restrict__ invn, int n) {
  int idx = blockIdx.x * 256 + threadIdx.x;
  if (idx >= n) return;
  int l = idx % L_TOT; int b = idx / L_TOT;
  int S, off; decode_l(l, S, off);
  int li = l - off; int ly = li / S, lx = li % S;
  float acc = 0.f;
  for (int dy = -1; dy <= 1; ++dy) {
    int ny = ly + dy; if (ny < 0 || ny >= S) continue;
    for (int dx = -1; dx <= 1; ++dx) {
      int nx = lx + dx; if (nx < 0 || nx >= S) continue;
      acc += ssq[(size_t)b * L_TOT + off + ny * S + nx];
    }
  }
  float nrm = sqrtf(acc); nrm = fmaxf(nrm, 1e-4f);
  invn[idx] = 1.f / nrm;
}

// ---------------- K5: B im2col (normalized key patches) bf16 [b][l][288], zero tail ----------------
__global__ void k_bim(const float* __restrict__ mref, const float* __restrict__ invn,
                      ushort_t* __restrict__ Bm, int n) {
  int idx = blockIdx.x * 256 + threadIdx.x;
  if (idx >= n) return;                      // n = 2*L_PADB*288
  int k = idx % 288; int l = (idx / 288) % L_PADB; int b = idx / (288 * L_PADB);
  float v = 0.f;
  if (l < L_TOT) {
    int c = k / 9; int r = k % 9; int dy = r / 3 - 1, dx = r % 3 - 1;
    int S, off; decode_l(l, S, off);
    int li = l - off; int ly = li / S, lx = li % S;
    int ny = ly + dy, nx = lx + dx;
    if (ny >= 0 && ny < S && nx >= 0 && nx < S)
      v = mref[(size_t)(b * 32 + c) * L_TOT + off + ny * S + nx] * invn[(size_t)b * L_TOT + l];
  }
  Bm[(size_t)(b * L_PADB + l) * 288 + k] = f2bf(v);
}

// ---------------- K6: A im2col (query patches) bf16 [b][p][288] ----------------
__global__ void k_aim(const float* __restrict__ mbb, ushort_t* __restrict__ Am, int n) {
  int idx = blockIdx.x * 256 + threadIdx.x;
  if (idx >= n) return;                      // n = 2*NPIX*288
  int k = idx % 288; int p = (idx / 288) % NPIX; int b = idx / (288 * NPIX);
  int c = k / 9; int r = k % 9; int dy = r / 3 - 1, dx = r % 3 - 1;
  int y = p / 64, x = p % 64;
  int ny = y + dy, nx = x + dx;
  float v = 0.f;
  if (ny >= 0 && ny < 64 && nx >= 0 && nx < 64)
    v = mbb[(size_t)(b * 32 + c) * NPIX + ny * 64 + nx];
  Am[(size_t)(b * NPIX + p) * 288 + k] = f2bf(v);
}

// ---------------- K7: R value patches -> pre-swizzled chunk blocks ----------------
// Rs[b][ch] = 36864 B: elem slot = col*32 + (seg ^ ((col>>1)&3))*8 + (l&7),
// seg = (l_local>>3). k_attn copies a chunk verbatim into LDS via global_load_lds.
__global__ void k_rs(const float* __restrict__ aref, ushort_t* __restrict__ Rs, int n) {
  int idx = blockIdx.x * 256 + threadIdx.x;
  if (idx >= n) return;                      // n = 2*417*576*32
  int e = idx & 7; int phys = (idx >> 3) & 3; int col = (idx >> 5) % 576;
  int ch = (idx >> 5) / 576 % NCHT; int b = idx / (32 * 576 * NCHT);
  int seg = phys ^ ((col >> 1) & 3);
  int l = ch * 32 + seg * 8 + e;
  float v = 0.f;
  if (l < L_TOT) {
    int c = col / 9; int r = col % 9; int dy = r / 3 - 1, dx = r % 3 - 1;
    int S, off; decode_l(l, S, off);
    int li = l - off; int ly = li / S, lx = li % S;
    int ny = ly + dy, nx = lx + dx;
    if (ny >= 0 && ny < S && nx >= 0 && nx < S)
      v = aref[(size_t)(b * 64 + c) * L_TOT + off + ny * S + nx];
  }
  Rs[idx] = f2bf(v);
}

// ---------------- K8: LDS-staged fused flash attention ----------------
// grid 512: blockIdx -> tile(7b) | split(1b) | b(1b). 256 thr = 4 waves.
// M=32 rows, Kc=32 l per chunk. S: wave(rb,cbh) computes 16 rows x 16 cols.
// Z: wave owns cols [wave*144, +144). R from dbuf LDS; B reg-prefetched.
__global__ __launch_bounds__(256, 2) void k_attn(const ushort_t* __restrict__ Am,
                                                 const ushort_t* __restrict__ Bm,
                                                 const ushort_t* __restrict__ Rs,
                                                 float* __restrict__ Og,
                                                 float* __restrict__ Om,
                                                 float* __restrict__ Ol) {
  __shared__ ushort_t Rlds[2][RCHUNK_E];   // 73728 B double-buffered R chunk
  __shared__ ushort_t Plds[32 * 32];       // 2 KB P tile (swizzled)
  __shared__ float Mx[2][32], Sx[2][32];
  int tid = threadIdx.x;
  int tile = blockIdx.x & 127; int split = (blockIdx.x >> 7) & 1; int b = blockIdx.x >> 8;
  int p0 = tile * 32;
  int wave = tid >> 6, lane = tid & 63, quad = lane >> 4, ln = lane & 15;
  int rb = wave & 1, cbh = wave >> 1;

  int c0 = split ? 209 : 0, c1 = split ? NCHT : 209;

  // A fragments resident (9 k-steps over K=288), rows p0 + rb*16 + ln
  bf16x8 af[9];
  {
    const ushort_t* arow = Am + (size_t)(b * NPIX + p0 + rb * 16 + ln) * 288;
    #pragma unroll
    for (int kk = 0; kk < 9; ++kk) af[kk] = *(const bf16x8*)(arow + kk * 32 + quad * 8);
  }

  f32x4 acc[2][9];
  #pragma unroll
  for (int h = 0; h < 2; ++h)
    #pragma unroll
    for (int t = 0; t < 9; ++t) { acc[h][t][0] = acc[h][t][1] = acc[h][t][2] = acc[h][t][3] = 0.f; }
  float mrun[2][4], lrun[4];
  #pragma unroll
  for (int h = 0; h < 2; ++h)
    #pragma unroll
    for (int r = 0; r < 4; ++r) mrun[h][r] = -1e30f;
  #pragma unroll
  for (int r = 0; r < 4; ++r) lrun[r] = 0.f;

  const ushort_t* RsB = Rs + (size_t)b * NCHT * RCHUNK_E + (size_t)(wave * 9) * 512 + lane * 8;
  const ushort_t* BmB = Bm + (size_t)b * L_PADB * 288 + quad * 8;

  // prologue: stage R chunk c0, load B frags c0
  {
    const ushort_t* src = RsB + (size_t)c0 * RCHUNK_E;
    ushort_t* dst = &Rlds[c0 & 1][wave * 9 * 512];
    #pragma unroll
    for (int i = 0; i < 9; ++i) gll16(src + i * 512, dst + i * 512);
  }
  bf16x8 bcur[9];
  {
    int col = c0 * 32 + cbh * 16 + ln;
    const ushort_t* brow = BmB + (size_t)col * 288;
    #pragma unroll
    for (int kk = 0; kk < 9; ++kk) bcur[kk] = *(const bf16x8*)(brow + kk * 32);
  }

  for (int ch = c0; ch < c1; ++ch) {
    int par = ch & 1;
    int cp = ch + 1 < NCHT ? ch + 1 : NCHT - 1;
    // (a) async-stage next R chunk into other buffer
    {
      const ushort_t* src = RsB + (size_t)cp * RCHUNK_E;
      ushort_t* dst = &Rlds[par ^ 1][wave * 9 * 512];
      #pragma unroll
      for (int i = 0; i < 9; ++i) gll16(src + i * 512, dst + i * 512);
    }
    // (b) S-MFMA from current B frags: 16 rows x 16 cols
    f32x4 s;
    s[0] = s[1] = s[2] = s[3] = 0.f;
    #pragma unroll
    for (int kk = 0; kk < 9; ++kk)
      s = __builtin_amdgcn_mfma_f32_16x16x32_bf16(af[kk], bcur[kk], s, 0, 0, 0);
    // (c) prefetch next B frags
    bf16x8 bnext[9];
    {
      int coln = cp * 32 + cbh * 16 + ln;
      if (coln > L_PADB - 1) coln = L_PADB - 1;
      const ushort_t* brow = BmB + (size_t)coln * 288;
      #pragma unroll
      for (int kk = 0; kk < 9; ++kk) bnext[kk] = *(const bf16x8*)(brow + kk * 32);
    }
    // (d) wave-local max over this wave's 16 cols
    int colw = ch * 32 + cbh * 16 + ln;
    bool valid = colw < L_TOT;
    float cm[4];
    #pragma unroll
    for (int r = 0; r < 4; ++r) cm[r] = valid ? s[r] : -1e30f;
    #pragma unroll
    for (int m = 1; m <= 8; m <<= 1)
      #pragma unroll
      for (int r = 0; r < 4; ++r) cm[r] = fmaxf(cm[r], __shfl_xor(cm[r], m));
    if (ln == 0) {
      #pragma unroll
      for (int r = 0; r < 4; ++r) Mx[cbh][rb * 16 + quad * 4 + r] = cm[r];
    }
    __syncthreads();   // B1
    // (e) alpha for all 32 rows; P = exp; write P (swizzled); partial sums
    float alpha[2][4]; bool chg = false;
    #pragma unroll
    for (int h = 0; h < 2; ++h)
      #pragma unroll
      for (int r = 0; r < 4; ++r) {
        int row = h * 16 + quad * 4 + r;
        float mc = fmaxf(Mx[0][row], Mx[1][row]);
        if (mc > mrun[h][r]) {
          alpha[h][r] = __expf(10.f * (mrun[h][r] - mc));
          mrun[h][r] = mc; chg = true;
        } else alpha[h][r] = 1.f;
      }
    float ps[4];
    #pragma unroll
    for (int r = 0; r < 4; ++r) {
      int row = rb * 16 + quad * 4 + r;
      float pv = valid ? __expf(10.f * (s[r] - mrun[rb][r])) : 0.f;
      int seg = cbh * 2 + (ln >> 3);
      int swz = seg ^ ((row >> 1) & 3);
      Plds[row * 32 + swz * 8 + (ln & 7)] = f2bf(pv);
      ps[r] = pv;
    }
    #pragma unroll
    for (int m = 1; m <= 8; m <<= 1)
      #pragma unroll
      for (int r = 0; r < 4; ++r) ps[r] += __shfl_xor(ps[r], m);
    if (ln == 0) {
      #pragma unroll
      for (int r = 0; r < 4; ++r) Sx[cbh][rb * 16 + quad * 4 + r] = ps[r];
    }
    // conditional rescale of Z acc (overlaps with barrier wait)
    if (__any(chg)) {
      #pragma unroll
      for (int h = 0; h < 2; ++h)
        #pragma unroll
        for (int t = 0; t < 9; ++t)
          #pragma unroll
          for (int r = 0; r < 4; ++r) acc[h][t][r] *= alpha[h][r];
    }
    __syncthreads();   // B2
    if (cbh == 0) {
      #pragma unroll
      for (int r = 0; r < 4; ++r) {
        int row = rb * 16 + quad * 4 + r;
        lrun[r] = lrun[r] * alpha[rb][r] + Sx[0][row] + Sx[1][row];
      }
    }
    // (f) Z-GEMM: P(32x32) @ R(32 x 144-per-wave) from LDS
    bf16x8 pf0, pf1;
    {
      int row0 = ln, row1 = 16 + ln;
      int sw0 = quad ^ ((row0 >> 1) & 3);
      int sw1 = quad ^ ((row1 >> 1) & 3);
      pf0 = *(const bf16x8*)&Plds[row0 * 32 + sw0 * 8];
      pf1 = *(const bf16x8*)&Plds[row1 * 32 + sw1 * 8];
    }
    #pragma unroll
    for (int t = 0; t < 9; ++t) {
      int col = wave * 144 + t * 16 + ln;
      int swz = quad ^ ((col >> 1) & 3);
      bf16x8 rf = *(const bf16x8*)&Rlds[par][col * 32 + swz * 8];
      acc[0][t] = __builtin_amdgcn_mfma_f32_16x16x32_bf16(pf0, rf, acc[0][t], 0, 0, 0);
      acc[1][t] = __builtin_amdgcn_mfma_f32_16x16x32_bf16(pf1, rf, acc[1][t], 0, 0, 0);
    }
    #pragma unroll
    for (int kk = 0; kk < 9; ++kk) bcur[kk] = bnext[kk];
  }

  // epilogue: unnormalized O + stats
  int sb = split * 2 + b;
  #pragma unroll
  for (int h = 0; h < 2; ++h)
    #pragma unroll
    for (int t = 0; t < 9; ++t) {
      int colg = wave * 144 + t * 16 + ln;
      #pragma unroll
      for (int r = 0; r < 4; ++r) {
        int row = p0 + h * 16 + quad * 4 + r;
        Og[((size_t)sb * NPIX + row) * 576 + colg] = acc[h][t][r];
      }
    }
  if (cbh == 0 && ln == 0) {
    #pragma unroll
    for (int r = 0; r < 4; ++r) {
      int row = p0 + rb * 16 + quad * 4 + r;
      Om[(size_t)sb * NPIX + row] = mrun[rb][r];
      Ol[(size_t)sb * NPIX + row] = lrun[r];
    }
  }
}

// ---------------- K9: per-pixel merge scales across the 2 splits ----------------
__global__ void k_scales(const float* __restrict__ Om, const float* __restrict__ Ol,
                         float* __restrict__ sc0, float* __restrict__ sc1, int n) {
  int idx = blockIdx.x * 256 + threadIdx.x;
  if (idx >= n) return;                      // n = 2*NPIX; idx = b*NPIX+p
  int b = idx / NPIX; int p = idx % NPIX;
  float m0 = Om[(size_t)b * NPIX + p],       l0 = Ol[(size_t)b * NPIX + p];
  float m1 = Om[(size_t)(2 + b) * NPIX + p], l1 = Ol[(size_t)(2 + b) * NPIX + p];
  float m = fmaxf(m0, m1);
  float e0 = expf(10.f * (m0 - m)), e1 = expf(10.f * (m1 - m));
  float inv = 1.f / (l0 * e0 + l1 * e1);
  sc0[idx] = e0 * inv; sc1[idx] = e1 * inv;
}

// ---------------- K10: 9-tap gather with split-merge, /4, + residual ----------------
__global__ void k_final(const float* __restrict__ Og, const float* __restrict__ sc0,
                        const float* __restrict__ sc1, const float* __restrict__ input,
                        float* __restrict__ out, int n) {
  int idx = blockIdx.x * 256 + threadIdx.x;
  if (idx >= n) return;                      // n = 2*64*NPIX, idx = ((b*64+c)*64+y)*64+x
  int x = idx & 63; int y = (idx >> 6) & 63; int c = (idx >> 12) & 63; int b = idx >> 18;
  float acc = 0.f;
  for (int j = 0; j < 3; ++j) {
    int qy = y + 1 - j; if (qy < 0 || qy >= 64) continue;
    for (int i = 0; i < 3; ++i) {
      int qx = x + 1 - i; if (qx < 0 || qx >= 64) continue;
      int p = qy * 64 + qx;
      size_t e = ((size_t)b * NPIX + p) * 576 + c * 9 + j * 3 + i;
      float z = Og[e] * sc0[b * NPIX + p]
              + Og[(size_t)2 * NPIX * 576 + e] * sc1[b * NPIX + p];
      acc += z;
    }
  }
  out[idx] = 0.25f * acc + input[idx];
}

extern "C" void kernel_launch(void* const* d_in, const int* in_sizes, int n_in,
                              void* d_out, int out_size, void* d_ws, size_t ws_size,
                              hipStream_t stream) {
  (void)in_sizes; (void)n_in; (void)out_size; (void)ws_size;
  const float* input = (const float*)d_in[0];
  const float* inref = (const float*)d_in[1];
  const float* Wb = (const float*)d_in[2];
  const float* bb = (const float*)d_in[3];
  const float* Wm = (const float*)d_in[4];
  const float* bm = (const float*)d_in[5];
  const float* Wa = (const float*)d_in[6];
  const float* ba = (const float*)d_in[7];
  const float* ap = (const float*)d_in[8];
  float* out = (float*)d_out;

  char* ws = (char*)d_ws;
  size_t off = 0;
  auto alloc = [&](size_t bytes) -> char* {
    char* p = ws + off; off = (off + bytes + 255) & ~(size_t)255; return p;
  };
  // persistent region
  ushort_t* Am = (ushort_t*)alloc((size_t)2 * NPIX * 288 * 2);        // 4.7 MB
  ushort_t* Bm = (ushort_t*)alloc((size_t)2 * L_PADB * 288 * 2);      // 15.4 MB
  ushort_t* Rs = (ushort_t*)alloc((size_t)2 * NCHT * RCHUNK_E * 2);   // 30.7 MB
  float*    Om = (float*)alloc((size_t)4 * NPIX * 4);
  float*    Ol = (float*)alloc((size_t)4 * NPIX * 4);
  float*    sc0 = (float*)alloc((size_t)2 * NPIX * 4);
  float*    sc1 = (float*)alloc((size_t)2 * NPIX * 4);
  // big region: Og (37.7 MB) aliases the early prep buffers (dead before k_attn)
  size_t og_bytes = (size_t)4 * NPIX * 576 * 4;
  char* big = alloc(og_bytes);
  float* Og = (float*)big;
  size_t eoff = 0;
  auto ealloc = [&](size_t bytes) -> char* {
    char* p = big + eoff; eoff = (eoff + bytes + 255) & ~(size_t)255; return p;
  };
  float* refbuf = (float*)ealloc((size_t)2 * 64 * L_TOT * 4);
  float* mref   = (float*)ealloc((size_t)2 * 32 * L_TOT * 4);
  float* aref   = (float*)ealloc((size_t)2 * 64 * L_TOT * 4);
  float* mbb    = (float*)ealloc((size_t)2 * 32 * NPIX * 4);
  float* ssq    = (float*)ealloc((size_t)2 * L_TOT * 4);
  float* invn   = (float*)ealloc((size_t)2 * L_TOT * 4);
  // total ws ~ 89 MB

  int n1 = 2 * 64 * L_TOT;
  k_resize<<<(n1 + 255) / 256, 256, 0, stream>>>(inref, refbuf, n1);
  int n2 = 2 * 96 * L_TOT;
  k_convref<<<(n2 + 255) / 256, 256, 0, stream>>>(refbuf, Wm, bm, Wa, ba, ap, mref, aref, n2);
  int n3 = 2 * 32 * NPIX;
  k_mb<<<(n3 + 255) / 256, 256, 0, stream>>>(input, Wb, bb, ap, mbb, n3);
  int n4 = 2 * L_TOT;
  k_ssq<<<(n4 + 255) / 256, 256, 0, stream>>>(mref, ssq, n4);
  k_invn<<<(n4 + 255) / 256, 256, 0, stream>>>(ssq, invn, n4);
  int n5 = 2 * L_PADB * 288;
  k_bim<<<(n5 + 255) / 256, 256, 0, stream>>>(mref, invn, Bm, n5);
  int n6 = 2 * NPIX * 288;
  k_aim<<<(n6 + 255) / 256, 256, 0, stream>>>(mbb, Am, n6);
  int n7 = 2 * NCHT * 576 * 32;
  k_rs<<<(n7 + 255) / 256, 256, 0, stream>>>(aref, Rs, n7);

  k_attn<<<512, 256, 0, stream>>>(Am, Bm, Rs, Og, Om, Ol);
  k_scales<<<(2 * NPIX + 255) / 256, 256, 0, stream>>>(Om, Ol, sc0, sc1, 2 * NPIX);
  int no = 2 * 64 * NPIX;
  k_final<<<(no + 255) / 256, 256, 0, stream>>>(Og, sc0, sc1, input, out, no);
}

// Round 5
// 667.661 us; speedup vs baseline: 1.9288x; 1.2435x over previous
//
#include <hip/hip_runtime.h>
#include <stdint.h>

// PyramidAttention gfx950 — round 5: static-row-max flash attention.
// m_row = max(0.7||q||, ||q||-7) precomputed -> no online max/rescale, ONE
// barrier per chunk (P tile dbuf), deferred row-sum (per-lane psum, reduced
// once at end). R via wave-private global_load_lds dbuf, swizzled (0 conflicts).

typedef __attribute__((ext_vector_type(8))) short bf16x8;
typedef __attribute__((ext_vector_type(4))) float f32x4;
typedef unsigned short ushort_t;

#define L_TOT  13326
#define L_PADB 13344   // 417 chunks * 32
#define NCHT   417
#define NPIX   4096
#define RCHUNK_E 18432 // 576 cols * 32 l
#define LOG2E10 14.4269504f   // 10*log2(e)

__device__ __forceinline__ float cubw(float d) {
  d = fabsf(d);
  if (d <= 1.f) return (1.25f * d - 2.25f) * d * d + 1.f;          // A=-0.75
  if (d < 2.f)  return ((-0.75f * d + 3.75f) * d - 6.f) * d + 3.f;
  return 0.f;
}

__device__ __forceinline__ void decode_l(int l, int& S, int& off) {
  if (l < 4096)       { S = 64; off = 0; }
  else if (l < 7345)  { S = 57; off = 4096; }
  else if (l < 9946)  { S = 51; off = 7345; }
  else if (l < 11882) { S = 44; off = 9946; }
  else                { S = 38; off = 11882; }
}

__device__ __forceinline__ ushort_t f2bf(float f) {
  union { float f; uint32_t u; } v; v.f = f;
  uint32_t r = (v.u + 0x7fffu + ((v.u >> 16) & 1u)) >> 16;  // RNE
  return (ushort_t)r;
}

__device__ __forceinline__ float preluf(float x, float a) { return x >= 0.f ? x : a * x; }

__device__ __forceinline__ void gll16(const ushort_t* g, ushort_t* l) {
  __builtin_amdgcn_global_load_lds(
      (const __attribute__((address_space(1))) unsigned int*)g,
      (__attribute__((address_space(3))) unsigned int*)l, 16, 0, 0);
}

// ---------------- K1: bicubic resize (align_corners=True, border clamp) ----------------
__global__ void k_resize(const float* __restrict__ inref, float* __restrict__ refbuf, int n) {
  int idx = blockIdx.x * 256 + threadIdx.x;
  if (idx >= n) return;                      // n = 2*64*L_TOT, idx -> (b*64+c, l)
  int l = idx % L_TOT; int bc = idx / L_TOT;
  int S, off; decode_l(l, S, off);
  int li = l - off; int ly = li / S, lx = li % S;
  float val;
  if (S == 64) {
    val = inref[(size_t)bc * 4096 + ly * 64 + lx];
  } else {
    float sc = (float)(63.0 / (double)(S - 1));
    float sy = (float)ly * sc, sx = (float)lx * sc;
    int iy = (int)floorf(sy), ix = (int)floorf(sx);
    float fy = sy - (float)iy, fx = sx - (float)ix;
    float wy[4] = { cubw(fy + 1.f), cubw(fy), cubw(1.f - fy), cubw(2.f - fy) };
    float wx[4] = { cubw(fx + 1.f), cubw(fx), cubw(1.f - fx), cubw(2.f - fx) };
    val = 0.f;
    for (int t = 0; t < 4; ++t) {
      int ty = iy - 1 + t; ty = ty < 0 ? 0 : (ty > 63 ? 63 : ty);
      float rv = 0.f;
      for (int u = 0; u < 4; ++u) {
        int tx = ix - 1 + u; tx = tx < 0 ? 0 : (tx > 63 ? 63 : tx);
        rv += wx[u] * inref[(size_t)bc * 4096 + ty * 64 + tx];
      }
      val += wy[t] * rv;
    }
  }
  refbuf[(size_t)bc * L_TOT + l] = val;
}

// ---------------- K2: conv1x1 (Wm->mref 32ch, Wa->aref 64ch) + prelu ----------------
__global__ void k_convref(const float* __restrict__ refbuf,
                          const float* __restrict__ Wm, const float* __restrict__ bm,
                          const float* __restrict__ Wa, const float* __restrict__ ba,
                          const float* __restrict__ ap,
                          float* __restrict__ mref, float* __restrict__ aref, int n) {
  int idx = blockIdx.x * 256 + threadIdx.x;
  if (idx >= n) return;                      // n = 2*96*L_TOT
  int l = idx % L_TOT; int ch = (idx / L_TOT) % 96; int b = idx / (96 * L_TOT);
  float a = ap[0];
  const float* base = refbuf + (size_t)b * 64 * L_TOT + l;
  const float* Wrow; float acc;
  if (ch < 32) { Wrow = Wm + ch * 64; acc = bm[ch]; }
  else         { Wrow = Wa + (ch - 32) * 64; acc = ba[ch - 32]; }
  for (int c = 0; c < 64; ++c) acc += Wrow[c] * base[(size_t)c * L_TOT];
  acc = preluf(acc, a);
  if (ch < 32) mref[(size_t)(b * 32 + ch) * L_TOT + l] = acc;
  else         aref[(size_t)(b * 64 + ch - 32) * L_TOT + l] = acc;
}

// ---------------- K3: match_base = prelu(Wb@input+bb) ----------------
__global__ void k_mb(const float* __restrict__ input, const float* __restrict__ Wb,
                     const float* __restrict__ bb, const float* __restrict__ ap,
                     float* __restrict__ mbb, int n) {
  int idx = blockIdx.x * 256 + threadIdx.x;
  if (idx >= n) return;                      // n = 2*32*NPIX
  int p = idx % NPIX; int cm = (idx / NPIX) % 32; int b = idx / (32 * NPIX);
  float a = ap[0];
  float acc = bb[cm];
  for (int c = 0; c < 64; ++c) acc += Wb[cm * 64 + c] * input[(size_t)(b * 64 + c) * NPIX + p];
  mbb[(size_t)(b * 32 + cm) * NPIX + p] = preluf(acc, a);
}

// ---------------- K4a: per-position sum of squares of mref (key side) ----------------
__global__ void k_ssq(const float* __restrict__ mref, float* __restrict__ ssq, int n) {
  int idx = blockIdx.x * 256 + threadIdx.x;
  if (idx >= n) return;                      // n = 2*L_TOT
  int l = idx % L_TOT; int b = idx / L_TOT;
  float s = 0.f;
  for (int c = 0; c < 32; ++c) { float v = mref[(size_t)(b * 32 + c) * L_TOT + l]; s += v * v; }
  ssq[idx] = s;
}

// ---------------- K4b: 3x3 window sum -> 1/max(sqrt, 1e-4) (key norm) ----------------
__global__ void k_invn(const float* __restrict__ ssq, float* __restrict__ invn, int n) {
  int idx = blockIdx.x * 256 + threadIdx.x;
  if (idx >= n) return;
  int l = idx % L_TOT; int b = idx / L_TOT;
  int S, off; decode_l(l, S, off);
  int li = l - off; int ly = li / S, lx = li % S;
  float acc = 0.f;
  for (int dy = -1; dy <= 1; ++dy) {
    int ny = ly + dy; if (ny < 0 || ny >= S) continue;
    for (int dx = -1; dx <= 1; ++dx) {
      int nx = lx + dx; if (nx < 0 || nx >= S) continue;
      acc += ssq[(size_t)b * L_TOT + off + ny * S + nx];
    }
  }
  float nrm = sqrtf(acc); nrm = fmaxf(nrm, 1e-4f);
  invn[idx] = 1.f / nrm;
}

// ---------------- K4c: per-pixel channel ssq of match_base (query side) ----------------
__global__ void k_ssqA(const float* __restrict__ mbb, float* __restrict__ ssqA, int n) {
  int idx = blockIdx.x * 256 + threadIdx.x;
  if (idx >= n) return;                      // n = 2*NPIX
  int p = idx % NPIX; int b = idx / NPIX;
  float s = 0.f;
  for (int c = 0; c < 32; ++c) { float v = mbb[(size_t)(b * 32 + c) * NPIX + p]; s += v * v; }
  ssqA[idx] = s;
}

// ---------------- K4d: 3x3 window (zero-pad) -> static log2-domain row max ----------------
// Mlog = 14.4269504 * max(0.7*||q||, ||q||-7): safe static softmax shift.
__global__ void k_m10(const float* __restrict__ ssqA, float* __restrict__ Mlog, int n) {
  int idx = blockIdx.x * 256 + threadIdx.x;
  if (idx >= n) return;                      // n = 2*NPIX
  int p = idx % NPIX; int b = idx / NPIX;
  int y = p / 64, x = p % 64;
  float acc = 0.f;
  for (int dy = -1; dy <= 1; ++dy) {
    int ny = y + dy; if (ny < 0 || ny >= 64) continue;
    for (int dx = -1; dx <= 1; ++dx) {
      int nx = x + dx; if (nx < 0 || nx >= 64) continue;
      acc += ssqA[(size_t)b * NPIX + ny * 64 + nx];
    }
  }
  float qn = sqrtf(acc);
  float m = fmaxf(0.7f * qn, qn - 7.f);
  Mlog[idx] = LOG2E10 * m;
}

// ---------------- K5: B im2col (normalized key patches) bf16 [b][l][288], zero tail ----------------
__global__ void k_bim(const float* __restrict__ mref, const float* __restrict__ invn,
                      ushort_t* __restrict__ Bm, int n) {
  int idx = blockIdx.x * 256 + threadIdx.x;
  if (idx >= n) return;                      // n = 2*L_PADB*288
  int k = idx % 288; int l = (idx / 288) % L_PADB; int b = idx / (288 * L_PADB);
  float v = 0.f;
  if (l < L_TOT) {
    int c = k / 9; int r = k % 9; int dy = r / 3 - 1, dx = r % 3 - 1;
    int S, off; decode_l(l, S, off);
    int li = l - off; int ly = li / S, lx = li % S;
    int ny = ly + dy, nx = lx + dx;
    if (ny >= 0 && ny < S && nx >= 0 && nx < S)
      v = mref[(size_t)(b * 32 + c) * L_TOT + off + ny * S + nx] * invn[(size_t)b * L_TOT + l];
  }
  Bm[(size_t)(b * L_PADB + l) * 288 + k] = f2bf(v);
}

// ---------------- K6: A im2col (query patches) bf16 [b][p][288] ----------------
__global__ void k_aim(const float* __restrict__ mbb, ushort_t* __restrict__ Am, int n) {
  int idx = blockIdx.x * 256 + threadIdx.x;
  if (idx >= n) return;                      // n = 2*NPIX*288
  int k = idx % 288; int p = (idx / 288) % NPIX; int b = idx / (288 * NPIX);
  int c = k / 9; int r = k % 9; int dy = r / 3 - 1, dx = r % 3 - 1;
  int y = p / 64, x = p % 64;
  int ny = y + dy, nx = x + dx;
  float v = 0.f;
  if (ny >= 0 && ny < 64 && nx >= 0 && nx < 64)
    v = mbb[(size_t)(b * 32 + c) * NPIX + ny * 64 + nx];
  Am[(size_t)(b * NPIX + p) * 288 + k] = f2bf(v);
}

// ---------------- K7: R value patches -> pre-swizzled chunk blocks ----------------
// Rs[b][ch]: slot = col*32 + (seg ^ ((col>>1)&3))*8 + (l&7), seg=(l_local>>3).
__global__ void k_rs(const float* __restrict__ aref, ushort_t* __restrict__ Rs, int n) {
  int idx = blockIdx.x * 256 + threadIdx.x;
  if (idx >= n) return;                      // n = 2*417*576*32
  int e = idx & 7; int phys = (idx >> 3) & 3; int col = (idx >> 5) % 576;
  int ch = (idx >> 5) / 576 % NCHT; int b = idx / (32 * 576 * NCHT);
  int seg = phys ^ ((col >> 1) & 3);
  int l = ch * 32 + seg * 8 + e;
  float v = 0.f;
  if (l < L_TOT) {
    int c = col / 9; int r = col % 9; int dy = r / 3 - 1, dx = r % 3 - 1;
    int S, off; decode_l(l, S, off);
    int li = l - off; int ly = li / S, lx = li % S;
    int ny = ly + dy, nx = lx + dx;
    if (ny >= 0 && ny < S && nx >= 0 && nx < S)
      v = aref[(size_t)(b * 64 + c) * L_TOT + off + ny * S + nx];
  }
  Rs[idx] = f2bf(v);
}

// ---------------- K8: static-max flash attention, one barrier per chunk ----------------
// grid 512: blockIdx -> tile(7b) | spl(1b) | b(1b). 256 thr = 4 waves.
// S: wave(rb,cbh) = 16 rows x 16 cols. Z: wave owns 144 cols, all 32 rows.
__global__ __launch_bounds__(256, 2) void k_attn(const ushort_t* __restrict__ Am,
                                                 const ushort_t* __restrict__ Bm,
                                                 const ushort_t* __restrict__ Rs,
                                                 const float* __restrict__ Mlog,
                                                 float* __restrict__ Og,
                                                 float* __restrict__ Ol) {
  __shared__ ushort_t Rlds[2][RCHUNK_E];   // 73728 B dbuf R chunk (wave-private slabs)
  __shared__ ushort_t Plds[2][1024];       // 4 KB dbuf P tile (swizzled)
  int tid = threadIdx.x;
  int tile = blockIdx.x & 127; int spl = (blockIdx.x >> 7) & 1; int b = blockIdx.x >> 8;
  int p0 = tile * 32;
  int wave = tid >> 6, lane = tid & 63, quad = lane >> 4, ln = lane & 15;
  int rb = wave & 1, cbh = wave >> 1;
  int c0 = spl ? 209 : 0, c1 = spl ? NCHT : 209;

  // A fragments resident; static row-max (log2 domain) for this wave's 4 rows
  bf16x8 af[9];
  {
    const ushort_t* arow = Am + (size_t)(b * NPIX + p0 + rb * 16 + ln) * 288;
    #pragma unroll
    for (int kk = 0; kk < 9; ++kk) af[kk] = *(const bf16x8*)(arow + kk * 32 + quad * 8);
  }
  float mlg[4];
  #pragma unroll
  for (int r = 0; r < 4; ++r)
    mlg[r] = Mlog[(size_t)b * NPIX + p0 + rb * 16 + quad * 4 + r];

  f32x4 acc[2][9];
  #pragma unroll
  for (int h = 0; h < 2; ++h)
    #pragma unroll
    for (int t = 0; t < 9; ++t) { acc[h][t][0] = acc[h][t][1] = acc[h][t][2] = acc[h][t][3] = 0.f; }
  float psum[4] = {0.f, 0.f, 0.f, 0.f};

  const ushort_t* RsB = Rs + (size_t)b * NCHT * RCHUNK_E + (size_t)(wave * 9) * 512 + lane * 8;
  const ushort_t* BmB = Bm + (size_t)b * L_PADB * 288 + quad * 8;

  // prologue: stage R chunk c0, load B frags c0
  {
    const ushort_t* src = RsB + (size_t)c0 * RCHUNK_E;
    ushort_t* dst = &Rlds[c0 & 1][wave * 9 * 512];
    #pragma unroll
    for (int i = 0; i < 9; ++i) gll16(src + i * 512, dst + i * 512);
  }
  bf16x8 bcur[9];
  {
    int col = c0 * 32 + cbh * 16 + ln;
    const ushort_t* brow = BmB + (size_t)col * 288;
    #pragma unroll
    for (int kk = 0; kk < 9; ++kk) bcur[kk] = *(const bf16x8*)(brow + kk * 32);
  }

  for (int ch = c0; ch < c1; ++ch) {
    int par = ch & 1;
    int cp = ch + 1 < NCHT ? ch + 1 : NCHT - 1;
    // stage next R chunk into other buffer (wave-private slab)
    {
      const ushort_t* src = RsB + (size_t)cp * RCHUNK_E;
      ushort_t* dst = &Rlds[par ^ 1][wave * 9 * 512];
      #pragma unroll
      for (int i = 0; i < 9; ++i) gll16(src + i * 512, dst + i * 512);
    }
    // S-MFMA: two independent accumulator chains (halve dep latency)
    f32x4 sa, sb;
    sa[0] = sa[1] = sa[2] = sa[3] = 0.f;
    sb[0] = sb[1] = sb[2] = sb[3] = 0.f;
    #pragma unroll
    for (int kk = 0; kk < 4; ++kk)
      sa = __builtin_amdgcn_mfma_f32_16x16x32_bf16(af[kk], bcur[kk], sa, 0, 0, 0);
    #pragma unroll
    for (int kk = 4; kk < 8; ++kk)
      sb = __builtin_amdgcn_mfma_f32_16x16x32_bf16(af[kk], bcur[kk], sb, 0, 0, 0);
    sa = __builtin_amdgcn_mfma_f32_16x16x32_bf16(af[8], bcur[8], sa, 0, 0, 0);
    // prefetch next B frags
    bf16x8 bnext[9];
    {
      int coln = cp * 32 + cbh * 16 + ln;
      const ushort_t* brow = BmB + (size_t)coln * 288;
      #pragma unroll
      for (int kk = 0; kk < 9; ++kk) bnext[kk] = *(const bf16x8*)(brow + kk * 32);
    }
    // P = 2^(14.43*s - Mlog); write swizzled dbuf P; accumulate deferred row-sum
    #pragma unroll
    for (int r = 0; r < 4; ++r) {
      float sv = sa[r] + sb[r];
      float pv = exp2f(fmaf(sv, LOG2E10, -mlg[r]));
      int row = rb * 16 + quad * 4 + r;
      int seg = cbh * 2 + (ln >> 3);
      int swz = seg ^ ((row >> 1) & 3);
      Plds[par][row * 32 + swz * 8 + (ln & 7)] = f2bf(pv);
      psum[r] += pv;
    }
    __syncthreads();   // P ready (only barrier per chunk)
    // Z-GEMM: P(32x32) @ R(32 x 144-per-wave) from LDS
    bf16x8 pf0, pf1;
    {
      int sw0 = quad ^ ((ln >> 1) & 3);
      int sw1 = quad ^ (((16 + ln) >> 1) & 3);
      pf0 = *(const bf16x8*)&Plds[par][ln * 32 + sw0 * 8];
      pf1 = *(const bf16x8*)&Plds[par][(16 + ln) * 32 + sw1 * 8];
    }
    #pragma unroll
    for (int t = 0; t < 9; ++t) {
      int col = wave * 144 + t * 16 + ln;
      int swz = quad ^ ((col >> 1) & 3);
      bf16x8 rf = *(const bf16x8*)&Rlds[par][col * 32 + swz * 8];
      acc[0][t] = __builtin_amdgcn_mfma_f32_16x16x32_bf16(pf0, rf, acc[0][t], 0, 0, 0);
      acc[1][t] = __builtin_amdgcn_mfma_f32_16x16x32_bf16(pf1, rf, acc[1][t], 0, 0, 0);
    }
    #pragma unroll
    for (int kk = 0; kk < 9; ++kk) bcur[kk] = bnext[kk];
  }

  // epilogue: reduce deferred row-sums over the 16 lanes of each quad
  #pragma unroll
  for (int m = 1; m <= 8; m <<= 1)
    #pragma unroll
    for (int r = 0; r < 4; ++r) psum[r] += __shfl_xor(psum[r], m);
  int sb2 = spl * 2 + b;
  if (ln == 0) {
    #pragma unroll
    for (int r = 0; r < 4; ++r) {
      int row = p0 + rb * 16 + quad * 4 + r;
      Ol[(size_t)(sb2 * 2 + cbh) * NPIX + row] = psum[r];
    }
  }
  // unnormalized O
  #pragma unroll
  for (int h = 0; h < 2; ++h)
    #pragma unroll
    for (int t = 0; t < 9; ++t) {
      int colg = wave * 144 + t * 16 + ln;
      #pragma unroll
      for (int r = 0; r < 4; ++r) {
        int row = p0 + h * 16 + quad * 4 + r;
        Og[((size_t)sb2 * NPIX + row) * 576 + colg] = acc[h][t][r];
      }
    }
}

// ---------------- K9: inv = 1 / sum of 4 partial row-sums (same static m everywhere) ----------------
__global__ void k_inv(const float* __restrict__ Ol, float* __restrict__ inv, int n) {
  int idx = blockIdx.x * 256 + threadIdx.x;
  if (idx >= n) return;                      // n = 2*NPIX; idx = b*NPIX+p
  int b = idx / NPIX; int p = idx % NPIX;
  float s = 0.f;
  #pragma unroll
  for (int spl = 0; spl < 2; ++spl)
    #pragma unroll
    for (int cbh = 0; cbh < 2; ++cbh)
      s += Ol[(size_t)(((spl * 2 + b) * 2) + cbh) * NPIX + p];
  inv[idx] = 1.f / s;
}

// ---------------- K10: 9-tap gather, split-sum, *inv, /4, + residual ----------------
__global__ void k_final(const float* __restrict__ Og, const float* __restrict__ inv,
                        const float* __restrict__ input, float* __restrict__ out, int n) {
  int idx = blockIdx.x * 256 + threadIdx.x;
  if (idx >= n) return;                      // n = 2*64*NPIX, idx = ((b*64+c)*64+y)*64+x
  int x = idx & 63; int y = (idx >> 6) & 63; int c = (idx >> 12) & 63; int b = idx >> 18;
  float acc = 0.f;
  for (int j = 0; j < 3; ++j) {
    int qy = y + 1 - j; if (qy < 0 || qy >= 64) continue;
    for (int i = 0; i < 3; ++i) {
      int qx = x + 1 - i; if (qx < 0 || qx >= 64) continue;
      int p = qy * 64 + qx;
      size_t e = ((size_t)b * NPIX + p) * 576 + c * 9 + j * 3 + i;
      float z = (Og[e] + Og[(size_t)2 * NPIX * 576 + e]) * inv[b * NPIX + p];
      acc += z;
    }
  }
  out[idx] = 0.25f * acc + input[idx];
}

extern "C" void kernel_launch(void* const* d_in, const int* in_sizes, int n_in,
                              void* d_out, int out_size, void* d_ws, size_t ws_size,
                              hipStream_t stream) {
  (void)in_sizes; (void)n_in; (void)out_size; (void)ws_size;
  const float* input = (const float*)d_in[0];
  const float* inref = (const float*)d_in[1];
  const float* Wb = (const float*)d_in[2];
  const float* bb = (const float*)d_in[3];
  const float* Wm = (const float*)d_in[4];
  const float* bm = (const float*)d_in[5];
  const float* Wa = (const float*)d_in[6];
  const float* ba = (const float*)d_in[7];
  const float* ap = (const float*)d_in[8];
  float* out = (float*)d_out;

  char* ws = (char*)d_ws;
  size_t off = 0;
  auto alloc = [&](size_t bytes) -> char* {
    char* p = ws + off; off = (off + bytes + 255) & ~(size_t)255; return p;
  };
  // persistent region
  ushort_t* Am  = (ushort_t*)alloc((size_t)2 * NPIX * 288 * 2);        // 4.7 MB
  ushort_t* Bm  = (ushort_t*)alloc((size_t)2 * L_PADB * 288 * 2);      // 15.4 MB
  ushort_t* Rs  = (ushort_t*)alloc((size_t)2 * NCHT * RCHUNK_E * 2);   // 30.7 MB
  float*    Ol  = (float*)alloc((size_t)8 * NPIX * 4);
  float*    inv = (float*)alloc((size_t)2 * NPIX * 4);
  float*    Mlog = (float*)alloc((size_t)2 * NPIX * 4);
  float*    ssqA = (float*)alloc((size_t)2 * NPIX * 4);
  // big region: Og (37.7 MB) aliases the early prep buffers (dead before k_attn)
  size_t og_bytes = (size_t)4 * NPIX * 576 * 4;
  char* big = alloc(og_bytes);
  float* Og = (float*)big;
  size_t eoff = 0;
  auto ealloc = [&](size_t bytes) -> char* {
    char* p = big + eoff; eoff = (eoff + bytes + 255) & ~(size_t)255; return p;
  };
  float* refbuf = (float*)ealloc((size_t)2 * 64 * L_TOT * 4);
  float* mref   = (float*)ealloc((size_t)2 * 32 * L_TOT * 4);
  float* aref   = (float*)ealloc((size_t)2 * 64 * L_TOT * 4);
  float* mbb    = (float*)ealloc((size_t)2 * 32 * NPIX * 4);
  float* ssq    = (float*)ealloc((size_t)2 * L_TOT * 4);
  float* invn   = (float*)ealloc((size_t)2 * L_TOT * 4);
  // total ws ~ 89 MB

  int n1 = 2 * 64 * L_TOT;
  k_resize<<<(n1 + 255) / 256, 256, 0, stream>>>(inref, refbuf, n1);
  int n2 = 2 * 96 * L_TOT;
  k_convref<<<(n2 + 255) / 256, 256, 0, stream>>>(refbuf, Wm, bm, Wa, ba, ap, mref, aref, n2);
  int n3 = 2 * 32 * NPIX;
  k_mb<<<(n3 + 255) / 256, 256, 0, stream>>>(input, Wb, bb, ap, mbb, n3);
  int n4 = 2 * L_TOT;
  k_ssq<<<(n4 + 255) / 256, 256, 0, stream>>>(mref, ssq, n4);
  k_invn<<<(n4 + 255) / 256, 256, 0, stream>>>(ssq, invn, n4);
  int n4a = 2 * NPIX;
  k_ssqA<<<(n4a + 255) / 256, 256, 0, stream>>>(mbb, ssqA, n4a);
  k_m10<<<(n4a + 255) / 256, 256, 0, stream>>>(ssqA, Mlog, n4a);
  int n5 = 2 * L_PADB * 288;
  k_bim<<<(n5 + 255) / 256, 256, 0, stream>>>(mref, invn, Bm, n5);
  int n6 = 2 * NPIX * 288;
  k_aim<<<(n6 + 255) / 256, 256, 0, stream>>>(mbb, Am, n6);
  int n7 = 2 * NCHT * 576 * 32;
  k_rs<<<(n7 + 255) / 256, 256, 0, stream>>>(aref, Rs, n7);

  k_attn<<<512, 256, 0, stream>>>(Am, Bm, Rs, Mlog, Og, Ol);
  k_inv<<<(2 * NPIX + 255) / 256, 256, 0, stream>>>(Ol, inv, 2 * NPIX);
  int no = 2 * 64 * NPIX;
  k_final<<<(no + 255) / 256, 256, 0, stream>>>(Og, inv, input, out, no);
}